// Round 1
// baseline (2114.853 us; speedup 1.0000x reference)
//
#include <hip/hip_runtime.h>
#include <cmath>

#define NB 4
#define LL 2048
#define DMODEL 1024
#define DINNER 2048
#define NROW (NB * LL)   // 8192
#define NSTATE 16
#define DCONV 4

__device__ __forceinline__ float silu_f(float x) {
    return x / (1.f + __expf(-x));
}

// C[m][n] = sum_k A[m*K+k] * B[n*K+k]   (A: MxK row-major, B: NxK row-major)
// 64x64 tile, BK=16, 256 threads, 4x4 micro-tile per thread.
__global__ __launch_bounds__(256) void gemm_abt(
    const float* __restrict__ A, const float* __restrict__ B,
    float* __restrict__ C, int N, int K) {
    __shared__ float As[16][68];
    __shared__ float Bs[16][68];
    const int tid = threadIdx.x;
    const int tx = tid & 15;          // 0..15 -> col group
    const int ty = tid >> 4;          // 0..15 -> row group
    const int lrow = tid >> 2;        // 0..63
    const int lk = (tid & 3) << 2;    // 0,4,8,12
    const float* Ap = A + (size_t)(blockIdx.y * 64 + lrow) * K + lk;
    const float* Bp = B + (size_t)(blockIdx.x * 64 + lrow) * K + lk;
    float acc[4][4] = {};
    for (int k0 = 0; k0 < K; k0 += 16) {
        float4 av = *(const float4*)(Ap + k0);
        float4 bv = *(const float4*)(Bp + k0);
        __syncthreads();
        As[lk + 0][lrow] = av.x; As[lk + 1][lrow] = av.y;
        As[lk + 2][lrow] = av.z; As[lk + 3][lrow] = av.w;
        Bs[lk + 0][lrow] = bv.x; Bs[lk + 1][lrow] = bv.y;
        Bs[lk + 2][lrow] = bv.z; Bs[lk + 3][lrow] = bv.w;
        __syncthreads();
#pragma unroll
        for (int k = 0; k < 16; ++k) {
            float4 a = *(const float4*)&As[k][ty << 2];
            float4 b = *(const float4*)&Bs[k][tx << 2];
            acc[0][0] += a.x * b.x; acc[0][1] += a.x * b.y;
            acc[0][2] += a.x * b.z; acc[0][3] += a.x * b.w;
            acc[1][0] += a.y * b.x; acc[1][1] += a.y * b.y;
            acc[1][2] += a.y * b.z; acc[1][3] += a.y * b.w;
            acc[2][0] += a.z * b.x; acc[2][1] += a.z * b.y;
            acc[2][2] += a.z * b.z; acc[2][3] += a.z * b.w;
            acc[3][0] += a.w * b.x; acc[3][1] += a.w * b.y;
            acc[3][2] += a.w * b.z; acc[3][3] += a.w * b.w;
        }
    }
    float* Cp = C + (size_t)(blockIdx.y * 64 + (ty << 2)) * N + blockIdx.x * 64 + (tx << 2);
#pragma unroll
    for (int i = 0; i < 4; ++i) {
        float4 o = make_float4(acc[i][0], acc[i][1], acc[i][2], acc[i][3]);
        *(float4*)(Cp + (size_t)i * N) = o;
    }
}

// Depthwise causal conv (DC=4) + bias + silu, plus row mean.
// One block per (b,l) row. xin is x_inner (NROW x 2*DINNER), first DINNER cols.
__global__ __launch_bounds__(256) void conv_silu_avg(
    const float* __restrict__ xin, const float* __restrict__ cw,
    const float* __restrict__ cb, float* __restrict__ xconv,
    float* __restrict__ xavg) {
    const int row = blockIdx.x;
    const int l = row & (LL - 1);
    const int tid = threadIdx.x;
    float lsum = 0.f;
    for (int d = tid; d < DINNER; d += 256) {
        float acc = cb[d];
#pragma unroll
        for (int k = 0; k < DCONV; ++k) {
            int ll = l - (DCONV - 1) + k;
            if (ll >= 0)
                acc += xin[(size_t)(row - (DCONV - 1) + k) * (2 * DINNER) + d] * cw[d * DCONV + k];
        }
        float v = silu_f(acc);
        xconv[(size_t)row * DINNER + d] = v;
        lsum += v;
    }
    __shared__ float red[256];
    red[tid] = lsum;
    __syncthreads();
    for (int s = 128; s > 0; s >>= 1) {
        if (tid < s) red[tid] += red[tid + s];
        __syncthreads();
    }
    if (tid == 0) xavg[row] = red[0] * (1.f / DINNER);
}

// Per (b,l) row: 48 dot products (delta/B/C, each 16 x K=2048), then
// a = exp(softplus(delta)*A), u = delta*Bs*xavg, keep Cs.
__global__ __launch_bounds__(256) void dbc_kernel(
    const float* __restrict__ xconv,
    const float* __restrict__ dw, const float* __restrict__ db,
    const float* __restrict__ bw, const float* __restrict__ cw,
    const float* __restrict__ A_log, const float* __restrict__ xavg,
    float* __restrict__ a_out, float* __restrict__ u_out,
    float* __restrict__ c_out) {
    const int row = blockIdx.x;
    const int tid = threadIdx.x;
    const int lane = tid & 63;
    const int wave = tid >> 6;
    __shared__ float lx[DINNER];
    __shared__ float res[48];
    for (int d = tid; d < DINNER; d += 256) lx[d] = xconv[(size_t)row * DINNER + d];
    __syncthreads();
#pragma unroll
    for (int i = 0; i < 12; ++i) {
        int n = wave * 12 + i;
        const float* wr = (n < 16) ? (dw + n * DINNER)
                        : (n < 32) ? (bw + (n - 16) * DINNER)
                                   : (cw + (n - 32) * DINNER);
        float p = 0.f;
        for (int k = lane; k < DINNER; k += 64) p += lx[k] * wr[k];
#pragma unroll
        for (int off = 32; off > 0; off >>= 1) p += __shfl_down(p, off);
        if (lane == 0) res[n] = p;
    }
    __syncthreads();
    if (tid < NSTATE) {
        int s = tid;
        float pre = res[s] + db[s];
        float delta = (pre > 20.f) ? pre : log1pf(__expf(pre));
        float Aa = -__expf(A_log[s]);
        float xa = xavg[row];
        a_out[row * NSTATE + s] = __expf(delta * Aa);
        u_out[row * NSTATE + s] = delta * res[16 + s] * xa;
        c_out[row * NSTATE + s] = res[32 + s];
    }
}

// Sequential scan: one wave, lane = b*16 + s. h_{l} = a_l*h_{l-1} + u_l.
__global__ __launch_bounds__(64) void scan_kernel(
    const float* __restrict__ a, const float* __restrict__ u,
    float* __restrict__ h_out) {
    const int lane = threadIdx.x;
    const int b = lane >> 4, s = lane & 15;
    float h = 0.f;
#pragma unroll 8
    for (int l = 0; l < LL; ++l) {
        int idx = (b * LL + l) * NSTATE + s;
        h = a[idx] * h + u[idx];
        h_out[idx] = h;
    }
}

// y[row] = sum_s h[row,s]*c[row,s]
__global__ __launch_bounds__(256) void yred_kernel(
    const float* __restrict__ h, const float* __restrict__ c,
    float* __restrict__ y) {
    int i = blockIdx.x * 256 + threadIdx.x;
    float s = 0.f;
#pragma unroll
    for (int k = 0; k < NSTATE; ++k) s += h[i * NSTATE + k] * c[i * NSTATE + k];
    y[i] = s;
}

// In-place: xconv[row,d] = y[row]*silu(x_gate[row,d]) + xconv[row,d]*D[d]
__global__ __launch_bounds__(256) void gate_skip(
    const float* __restrict__ xin, const float* __restrict__ y,
    const float* __restrict__ Dv, float* __restrict__ xconv) {
    int i = (blockIdx.x * 256 + threadIdx.x) * 4;
    int row = i >> 11;           // DINNER = 2048
    int d = i & (DINNER - 1);
    float4 g = *(const float4*)&xin[(size_t)row * (2 * DINNER) + DINNER + d];
    float4 xc = *(const float4*)&xconv[(size_t)row * DINNER + d];
    float4 dv = *(const float4*)&Dv[d];
    float yv = y[row];
    float4 o;
    o.x = yv * silu_f(g.x) + xc.x * dv.x;
    o.y = yv * silu_f(g.y) + xc.y * dv.y;
    o.z = yv * silu_f(g.z) + xc.z * dv.z;
    o.w = yv * silu_f(g.w) + xc.w * dv.w;
    *(float4*)&xconv[(size_t)row * DINNER + d] = o;
}

extern "C" void kernel_launch(void* const* d_in, const int* in_sizes, int n_in,
                              void* d_out, int out_size, void* d_ws, size_t ws_size,
                              hipStream_t stream) {
    const float* x       = (const float*)d_in[0];
    const float* w_in    = (const float*)d_in[1];
    const float* conv_w  = (const float*)d_in[2];
    const float* conv_b  = (const float*)d_in[3];
    const float* A_log   = (const float*)d_in[4];
    const float* Dv      = (const float*)d_in[5];
    const float* delta_w = (const float*)d_in[6];
    const float* delta_b = (const float*)d_in[7];
    const float* B_w     = (const float*)d_in[8];
    const float* C_w     = (const float*)d_in[9];
    const float* out_w   = (const float*)d_in[10];
    float* out = (float*)d_out;

    float* ws = (float*)d_ws;
    float* xinner = ws;                                        // NROW * 4096
    float* xconv  = xinner + (size_t)NROW * 2 * DINNER;        // NROW * 2048
    float* abuf   = xconv + (size_t)NROW * DINNER;             // NROW * 16
    float* ubuf   = abuf + NROW * NSTATE;
    float* cbuf   = ubuf + NROW * NSTATE;
    float* hbuf   = cbuf + NROW * NSTATE;
    float* ybuf   = hbuf + NROW * NSTATE;                      // NROW
    float* avgbuf = ybuf + NROW;                               // NROW

    // 1. x_inner = x @ in_proj_w.T    (8192 x 1024) @ (4096 x 1024)^T
    gemm_abt<<<dim3((2 * DINNER) / 64, NROW / 64), 256, 0, stream>>>(
        x, w_in, xinner, 2 * DINNER, DMODEL);
    // 2. conv + silu + row-mean
    conv_silu_avg<<<NROW, 256, 0, stream>>>(xinner, conv_w, conv_b, xconv, avgbuf);
    // 3. delta/B/C projections -> a, u, c
    dbc_kernel<<<NROW, 256, 0, stream>>>(xconv, delta_w, delta_b, B_w, C_w,
                                         A_log, avgbuf, abuf, ubuf, cbuf);
    // 4. sequential scan
    scan_kernel<<<1, 64, 0, stream>>>(abuf, ubuf, hbuf);
    // 5. y = sum_s h*c
    yred_kernel<<<NROW / 256, 256, 0, stream>>>(hbuf, cbuf, ybuf);
    // 6. gating + skip, in-place into xconv
    gate_skip<<<(NROW * DINNER / 4) / 256, 256, 0, stream>>>(xinner, ybuf, Dv, xconv);
    // 7. out = y_skip @ out_proj_w.T   (8192 x 2048) @ (1024 x 2048)^T
    gemm_abt<<<dim3(DMODEL / 64, NROW / 64), 256, 0, stream>>>(
        xconv, out_w, out, DMODEL, DINNER);
}

// Round 2
// 567.881 us; speedup vs baseline: 3.7241x; 3.7241x over previous
//
#include <hip/hip_runtime.h>
#include <cmath>

#define LL 2048
#define NROW 8192
#define DMODEL 1024
#define DINNER 2048
#define NSTATE 16

typedef unsigned short u16;
typedef __attribute__((ext_vector_type(8))) unsigned short u16x8;
typedef __attribute__((ext_vector_type(8))) short short8;
typedef __attribute__((ext_vector_type(4))) float floatx4;

__device__ __forceinline__ float bf2f(u16 h) {
    unsigned u = ((unsigned)h) << 16;
    float f;
    __builtin_memcpy(&f, &u, 4);
    return f;
}
__device__ __forceinline__ u16 f2bf(float f) {
    unsigned u;
    __builtin_memcpy(&u, &f, 4);
    u = u + 0x7fffu + ((u >> 16) & 1u);
    return (u16)(u >> 16);
}
__device__ __forceinline__ float silu_f(float x) { return x / (1.f + __expf(-x)); }

// fp32 -> bf16 (RNE), 8 elems/thread
__global__ __launch_bounds__(256) void cvt_bf16(const float* __restrict__ in,
                                                u16* __restrict__ out) {
    size_t i = ((size_t)blockIdx.x * 256 + threadIdx.x) * 8;
    float4 a = *(const float4*)&in[i];
    float4 b = *(const float4*)&in[i + 4];
    u16x8 o;
    o[0] = f2bf(a.x); o[1] = f2bf(a.y); o[2] = f2bf(a.z); o[3] = f2bf(a.w);
    o[4] = f2bf(b.x); o[5] = f2bf(b.y); o[6] = f2bf(b.z); o[7] = f2bf(b.w);
    *(u16x8*)&out[i] = o;
}

// C[m][n] = sum_k A[m,k]*B[n,k]; A: MxK bf16, B: NxK bf16, both row-major.
// 128x128 tile, BK=32, 4 waves (2x2), each wave 64x64 via 4x4 of 16x16x32 MFMA.
// LDS layout: row-major [128][32] bf16, with the four 16B k-blocks of each row
// XOR-swizzled by ((row>>1)&3) so frag ds_read_b128 spreads over 8 bank groups.
template <int OUT_BF16>
__global__ __launch_bounds__(256) void gemm_bt_mfma(
    const u16* __restrict__ A, const u16* __restrict__ B,
    void* __restrict__ Cout, int N, int K) {
    __shared__ u16 As[128 * 32];
    __shared__ u16 Bs[128 * 32];
    const int tid = threadIdx.x;
    const int lane = tid & 63;
    const int wave = tid >> 6;
    const int bm = blockIdx.y * 128;
    const int bn = blockIdx.x * 128;

    // --- staging setup: chunk c=wave*2+p covers tile rows [c*16, c*16+16) ---
    // lane slot in chunk: row = c*16 + (lane>>2); holds swizzled k-block
    const int kbg = (lane & 3) ^ ((lane >> 3) & 3);  // global k-block this lane fetches
    const int srow = lane >> 2;
    const u16* ag[2];
    const u16* bg[2];
#pragma unroll
    for (int p = 0; p < 2; ++p) {
        int c = wave * 2 + p;
        ag[p] = A + (size_t)(bm + c * 16 + srow) * K + kbg * 8;
        bg[p] = B + (size_t)(bn + c * 16 + srow) * K + kbg * 8;
    }
    // --- fragment read setup (constant across K loop) ---
    const int fr = lane & 15;
    const int kb = lane >> 4;
    const int kbs = kb ^ ((fr >> 1) & 3);  // swizzled k-block to read
    const int wr = (wave >> 1) * 64;
    const int wc = (wave & 1) * 64;
    int aoff[4], boff[4];
#pragma unroll
    for (int i = 0; i < 4; ++i) {
        aoff[i] = (wr + i * 16 + fr) * 32 + kbs * 8;
        boff[i] = (wc + i * 16 + fr) * 32 + kbs * 8;
    }
    floatx4 acc[4][4];
#pragma unroll
    for (int i = 0; i < 4; ++i)
#pragma unroll
        for (int j = 0; j < 4; ++j) acc[i][j] = (floatx4){0.f, 0.f, 0.f, 0.f};

    for (int k0 = 0; k0 < K; k0 += 32) {
        __syncthreads();
#pragma unroll
        for (int p = 0; p < 2; ++p) {
            int c = wave * 2 + p;
            __builtin_amdgcn_global_load_lds(
                (const __attribute__((address_space(1))) void*)ag[p],
                (__attribute__((address_space(3))) void*)&As[c * 512], 16, 0, 0);
            __builtin_amdgcn_global_load_lds(
                (const __attribute__((address_space(1))) void*)bg[p],
                (__attribute__((address_space(3))) void*)&Bs[c * 512], 16, 0, 0);
            ag[p] += 32;
            bg[p] += 32;
        }
        __syncthreads();
        short8 af[4], bf[4];
#pragma unroll
        for (int i = 0; i < 4; ++i) af[i] = *(const short8*)&As[aoff[i]];
#pragma unroll
        for (int j = 0; j < 4; ++j) bf[j] = *(const short8*)&Bs[boff[j]];
#pragma unroll
        for (int i = 0; i < 4; ++i)
#pragma unroll
            for (int j = 0; j < 4; ++j)
                acc[i][j] = __builtin_amdgcn_mfma_f32_16x16x32_bf16(af[i], bf[j],
                                                                    acc[i][j], 0, 0, 0);
    }
    // epilogue: C/D layout col=lane&15, row=(lane>>4)*4+reg
    const int cr = (lane >> 4) * 4;
    const int cc = lane & 15;
#pragma unroll
    for (int i = 0; i < 4; ++i)
#pragma unroll
        for (int j = 0; j < 4; ++j)
#pragma unroll
            for (int r = 0; r < 4; ++r) {
                int grow = bm + wr + i * 16 + cr + r;
                int gcol = bn + wc + j * 16 + cc;
                float v = acc[i][j][r];
                if (OUT_BF16)
                    ((u16*)Cout)[(size_t)grow * N + gcol] = f2bf(v);
                else
                    ((float*)Cout)[(size_t)grow * N + gcol] = v;
            }
}

// depthwise causal conv (DC=4) + bias + silu + row-mean. bf16 in/out.
__global__ __launch_bounds__(256) void conv_silu_avg(
    const u16* __restrict__ xin, const float* __restrict__ cw,
    const float* __restrict__ cb, u16* __restrict__ xconv,
    float* __restrict__ xavg) {
    const int row = blockIdx.x;
    const int l = row & (LL - 1);
    const int tid = threadIdx.x;
    const int d0 = tid * 8;
    float acc[8];
#pragma unroll
    for (int e = 0; e < 8; e += 4) {
        float4 c = *(const float4*)&cb[d0 + e];
        acc[e] = c.x; acc[e + 1] = c.y; acc[e + 2] = c.z; acc[e + 3] = c.w;
    }
    float4 cwv[8];
#pragma unroll
    for (int e = 0; e < 8; ++e) cwv[e] = *(const float4*)&cw[(d0 + e) * 4];
#pragma unroll
    for (int k = 0; k < 4; ++k) {
        if (l - 3 + k >= 0) {
            u16x8 v = *(const u16x8*)&xin[(size_t)(row - 3 + k) * (2 * DINNER) + d0];
#pragma unroll
            for (int e = 0; e < 8; ++e)
                acc[e] += bf2f(v[e]) * ((const float*)&cwv[e])[k];
        }
    }
    float lsum = 0.f;
    u16x8 o;
#pragma unroll
    for (int e = 0; e < 8; ++e) {
        float s = silu_f(acc[e]);
        lsum += s;
        o[e] = f2bf(s);
    }
    *(u16x8*)&xconv[(size_t)row * DINNER + d0] = o;
    const int lane = tid & 63, wave = tid >> 6;
#pragma unroll
    for (int off = 32; off; off >>= 1) lsum += __shfl_down(lsum, off);
    __shared__ float wred[4];
    if (lane == 0) wred[wave] = lsum;
    __syncthreads();
    if (tid == 0) xavg[row] = (wred[0] + wred[1] + wred[2] + wred[3]) * (1.f / DINNER);
}

// delta/B/C projections for 8 rows per block; wave w computes 12 of the 48 outputs.
__global__ __launch_bounds__(256) void dbc_kernel(
    const u16* __restrict__ xconv, const float* __restrict__ dw,
    const float* __restrict__ db, const float* __restrict__ bw,
    const float* __restrict__ cw, const float* __restrict__ A_log,
    const float* __restrict__ xavg,
    float* __restrict__ a_out, float* __restrict__ u_out, float* __restrict__ c_out) {
    const int row0 = blockIdx.x * 8;
    const int tid = threadIdx.x;
    const int lane = tid & 63;
    const int wave = tid >> 6;
    __shared__ float res[48][8];
    const float* wp[12];
#pragma unroll
    for (int i = 0; i < 12; ++i) {
        int n = wave * 12 + i;
        wp[i] = (n < 16) ? (dw + (size_t)n * DINNER)
              : (n < 32) ? (bw + (size_t)(n - 16) * DINNER)
                         : (cw + (size_t)(n - 32) * DINNER);
    }
    float acc[12][8];
#pragma unroll
    for (int i = 0; i < 12; ++i)
#pragma unroll
        for (int r = 0; r < 8; ++r) acc[i][r] = 0.f;
    for (int k = lane; k < DINNER; k += 64) {
        float xv[8];
#pragma unroll
        for (int r = 0; r < 8; ++r) xv[r] = bf2f(xconv[(size_t)(row0 + r) * DINNER + k]);
#pragma unroll
        for (int i = 0; i < 12; ++i) {
            float w = wp[i][k];
#pragma unroll
            for (int r = 0; r < 8; ++r) acc[i][r] += xv[r] * w;
        }
    }
#pragma unroll
    for (int off = 32; off; off >>= 1)
#pragma unroll
        for (int i = 0; i < 12; ++i)
#pragma unroll
            for (int r = 0; r < 8; ++r) acc[i][r] += __shfl_down(acc[i][r], off);
    if (lane == 0) {
#pragma unroll
        for (int i = 0; i < 12; ++i)
#pragma unroll
            for (int r = 0; r < 8; ++r) res[wave * 12 + i][r] = acc[i][r];
    }
    __syncthreads();
    if (tid < 128) {
        int r = tid >> 4, s = tid & 15;
        int row = row0 + r;
        float pre = res[s][r] + db[s];
        float delta = (pre > 20.f) ? pre : log1pf(__expf(pre));
        float Aa = -__expf(A_log[s]);
        a_out[row * NSTATE + s] = __expf(delta * Aa);
        u_out[row * NSTATE + s] = delta * res[16 + s][r] * xavg[row];
        c_out[row * NSTATE + s] = res[32 + s][r];
    }
}

// sequential scan: one wave, lane = b*16 + s
__global__ __launch_bounds__(64) void scan_kernel(
    const float* __restrict__ a, const float* __restrict__ u,
    float* __restrict__ h_out) {
    const int lane = threadIdx.x;
    const int b = lane >> 4, s = lane & 15;
    float h = 0.f;
#pragma unroll 8
    for (int l = 0; l < LL; ++l) {
        int idx = (b * LL + l) * NSTATE + s;
        h = fmaf(a[idx], h, u[idx]);
        h_out[idx] = h;
    }
}

__global__ __launch_bounds__(256) void yred_kernel(
    const float* __restrict__ h, const float* __restrict__ c,
    float* __restrict__ y) {
    int i = blockIdx.x * 256 + threadIdx.x;
    float s = 0.f;
#pragma unroll
    for (int k = 0; k < NSTATE; ++k) s += h[i * NSTATE + k] * c[i * NSTATE + k];
    y[i] = s;
}

// y_skip = y*silu(x_gate) + x_conv*D  -> bf16
__global__ __launch_bounds__(256) void gate_skip(
    const u16* __restrict__ xin, const float* __restrict__ y,
    const float* __restrict__ Dv, const u16* __restrict__ xconv,
    u16* __restrict__ yskip) {
    size_t i = ((size_t)blockIdx.x * 256 + threadIdx.x) * 8;
    int row = (int)(i >> 11);
    int d = (int)(i & (DINNER - 1));
    u16x8 g = *(const u16x8*)&xin[(size_t)row * (2 * DINNER) + DINNER + d];
    u16x8 xc = *(const u16x8*)&xconv[i];
    float yv = y[row];
    u16x8 o;
#pragma unroll
    for (int e = 0; e < 8; ++e) {
        float gv = silu_f(bf2f(g[e]));
        float v = yv * gv + bf2f(xc[e]) * Dv[d + e];
        o[e] = f2bf(v);
    }
    *(u16x8*)&yskip[i] = o;
}

extern "C" void kernel_launch(void* const* d_in, const int* in_sizes, int n_in,
                              void* d_out, int out_size, void* d_ws, size_t ws_size,
                              hipStream_t stream) {
    const float* x       = (const float*)d_in[0];
    const float* w_in    = (const float*)d_in[1];
    const float* conv_w  = (const float*)d_in[2];
    const float* conv_b  = (const float*)d_in[3];
    const float* A_log   = (const float*)d_in[4];
    const float* Dv      = (const float*)d_in[5];
    const float* delta_w = (const float*)d_in[6];
    const float* delta_b = (const float*)d_in[7];
    const float* B_w     = (const float*)d_in[8];
    const float* C_w     = (const float*)d_in[9];
    const float* out_w   = (const float*)d_in[10];
    float* out = (float*)d_out;

    u16* xb  = (u16*)d_ws;                 // 8192*1024
    u16* wb  = xb + 8388608;               // 4096*1024
    u16* owb = wb + 4194304;               // 1024*2048
    u16* xin = owb + 2097152;              // 8192*4096
    u16* xcv = xin + 33554432;             // 8192*2048
    u16* ysk = xcv + 16777216;             // 8192*2048
    float* fb     = (float*)(ysk + 16777216);
    float* abuf   = fb;                    // 8192*16
    float* ubuf   = abuf + 131072;
    float* cbuf   = ubuf + 131072;
    float* hbuf   = cbuf + 131072;
    float* ybuf   = hbuf + 131072;         // 8192
    float* avgbuf = ybuf + 8192;           // 8192

    cvt_bf16<<<4096, 256, 0, stream>>>(x, xb);
    cvt_bf16<<<2048, 256, 0, stream>>>(w_in, wb);
    cvt_bf16<<<1024, 256, 0, stream>>>(out_w, owb);

    // x_inner = x @ in_proj_w.T : (8192x1024)@(4096x1024)^T -> bf16
    gemm_bt_mfma<1><<<dim3(32, 64), 256, 0, stream>>>(xb, wb, xin, 2 * DINNER, DMODEL);

    conv_silu_avg<<<NROW, 256, 0, stream>>>(xin, conv_w, conv_b, xcv, avgbuf);
    dbc_kernel<<<NROW / 8, 256, 0, stream>>>(xcv, delta_w, delta_b, B_w, C_w,
                                             A_log, avgbuf, abuf, ubuf, cbuf);
    scan_kernel<<<1, 64, 0, stream>>>(abuf, ubuf, hbuf);
    yred_kernel<<<NROW / 256, 256, 0, stream>>>(hbuf, cbuf, ybuf);
    gate_skip<<<NROW * DINNER / 8 / 256, 256, 0, stream>>>(xin, ybuf, Dv, xcv, ysk);

    // out = y_skip @ out_proj_w.T : (8192x2048)@(1024x2048)^T -> fp32
    gemm_bt_mfma<0><<<dim3(8, 64), 256, 0, stream>>>(ysk, owb, out, DMODEL, DINNER);
}

// Round 3
// 432.736 us; speedup vs baseline: 4.8872x; 1.3123x over previous
//
#include <hip/hip_runtime.h>
#include <cmath>

#define LL 2048
#define NROW 8192
#define DMODEL 1024
#define DINNER 2048
#define NSTATE 16
#define NSEG 64
#define SEGLEN 32   // NSEG * SEGLEN == LL

typedef unsigned short u16;
typedef __attribute__((ext_vector_type(8))) unsigned short u16x8;
typedef __attribute__((ext_vector_type(8))) short short8;
typedef __attribute__((ext_vector_type(4))) float floatx4;

__device__ __forceinline__ float bf2f(u16 h) {
    unsigned u = ((unsigned)h) << 16;
    float f;
    __builtin_memcpy(&f, &u, 4);
    return f;
}
__device__ __forceinline__ u16 f2bf(float f) {
    unsigned u;
    __builtin_memcpy(&u, &f, 4);
    u = u + 0x7fffu + ((u >> 16) & 1u);
    return (u16)(u >> 16);
}
__device__ __forceinline__ float silu_f(float x) { return x / (1.f + __expf(-x)); }

// fp32 -> bf16 (RNE), 8 elems/thread
__global__ __launch_bounds__(256) void cvt_bf16(const float* __restrict__ in,
                                                u16* __restrict__ out) {
    size_t i = ((size_t)blockIdx.x * 256 + threadIdx.x) * 8;
    float4 a = *(const float4*)&in[i];
    float4 b = *(const float4*)&in[i + 4];
    u16x8 o;
    o[0] = f2bf(a.x); o[1] = f2bf(a.y); o[2] = f2bf(a.z); o[3] = f2bf(a.w);
    o[4] = f2bf(b.x); o[5] = f2bf(b.y); o[6] = f2bf(b.z); o[7] = f2bf(b.w);
    *(u16x8*)&out[i] = o;
}

// C[m][n] = sum_k A[m,k]*B[n,k]; A: MxK bf16, B: NxK bf16, both row-major.
// 128x128 tile, BK=32, 4 waves (2x2), each wave 64x64 via 4x4 of 16x16x32 MFMA.
template <int OUT_BF16>
__global__ __launch_bounds__(256) void gemm_bt_mfma(
    const u16* __restrict__ A, const u16* __restrict__ B,
    void* __restrict__ Cout, int N, int K) {
    __shared__ u16 As[128 * 32];
    __shared__ u16 Bs[128 * 32];
    const int tid = threadIdx.x;
    const int lane = tid & 63;
    const int wave = tid >> 6;
    const int bm = blockIdx.y * 128;
    const int bn = blockIdx.x * 128;

    const int kbg = (lane & 3) ^ ((lane >> 3) & 3);
    const int srow = lane >> 2;
    const u16* ag[2];
    const u16* bg[2];
#pragma unroll
    for (int p = 0; p < 2; ++p) {
        int c = wave * 2 + p;
        ag[p] = A + (size_t)(bm + c * 16 + srow) * K + kbg * 8;
        bg[p] = B + (size_t)(bn + c * 16 + srow) * K + kbg * 8;
    }
    const int fr = lane & 15;
    const int kb = lane >> 4;
    const int kbs = kb ^ ((fr >> 1) & 3);
    const int wr = (wave >> 1) * 64;
    const int wc = (wave & 1) * 64;
    int aoff[4], boff[4];
#pragma unroll
    for (int i = 0; i < 4; ++i) {
        aoff[i] = (wr + i * 16 + fr) * 32 + kbs * 8;
        boff[i] = (wc + i * 16 + fr) * 32 + kbs * 8;
    }
    floatx4 acc[4][4];
#pragma unroll
    for (int i = 0; i < 4; ++i)
#pragma unroll
        for (int j = 0; j < 4; ++j) acc[i][j] = (floatx4){0.f, 0.f, 0.f, 0.f};

    for (int k0 = 0; k0 < K; k0 += 32) {
        __syncthreads();
#pragma unroll
        for (int p = 0; p < 2; ++p) {
            int c = wave * 2 + p;
            __builtin_amdgcn_global_load_lds(
                (const __attribute__((address_space(1))) void*)ag[p],
                (__attribute__((address_space(3))) void*)&As[c * 512], 16, 0, 0);
            __builtin_amdgcn_global_load_lds(
                (const __attribute__((address_space(1))) void*)bg[p],
                (__attribute__((address_space(3))) void*)&Bs[c * 512], 16, 0, 0);
            ag[p] += 32;
            bg[p] += 32;
        }
        __syncthreads();
        short8 af[4], bf[4];
#pragma unroll
        for (int i = 0; i < 4; ++i) af[i] = *(const short8*)&As[aoff[i]];
#pragma unroll
        for (int j = 0; j < 4; ++j) bf[j] = *(const short8*)&Bs[boff[j]];
#pragma unroll
        for (int i = 0; i < 4; ++i)
#pragma unroll
            for (int j = 0; j < 4; ++j)
                acc[i][j] = __builtin_amdgcn_mfma_f32_16x16x32_bf16(af[i], bf[j],
                                                                    acc[i][j], 0, 0, 0);
    }
    const int cr = (lane >> 4) * 4;
    const int cc = lane & 15;
#pragma unroll
    for (int i = 0; i < 4; ++i)
#pragma unroll
        for (int j = 0; j < 4; ++j)
#pragma unroll
            for (int r = 0; r < 4; ++r) {
                int grow = bm + wr + i * 16 + cr + r;
                int gcol = bn + wc + j * 16 + cc;
                float v = acc[i][j][r];
                if (OUT_BF16)
                    ((u16*)Cout)[(size_t)grow * N + gcol] = f2bf(v);
                else
                    ((float*)Cout)[(size_t)grow * N + gcol] = v;
            }
}

// depthwise causal conv (DC=4) + bias + silu + row-mean. bf16 in/out.
__global__ __launch_bounds__(256) void conv_silu_avg(
    const u16* __restrict__ xin, const float* __restrict__ cw,
    const float* __restrict__ cb, u16* __restrict__ xconv,
    float* __restrict__ xavg) {
    const int row = blockIdx.x;
    const int l = row & (LL - 1);
    const int tid = threadIdx.x;
    const int d0 = tid * 8;
    float acc[8];
#pragma unroll
    for (int e = 0; e < 8; e += 4) {
        float4 c = *(const float4*)&cb[d0 + e];
        acc[e] = c.x; acc[e + 1] = c.y; acc[e + 2] = c.z; acc[e + 3] = c.w;
    }
    float4 cwv[8];
#pragma unroll
    for (int e = 0; e < 8; ++e) cwv[e] = *(const float4*)&cw[(d0 + e) * 4];
#pragma unroll
    for (int k = 0; k < 4; ++k) {
        if (l - 3 + k >= 0) {
            u16x8 v = *(const u16x8*)&xin[(size_t)(row - 3 + k) * (2 * DINNER) + d0];
#pragma unroll
            for (int e = 0; e < 8; ++e)
                acc[e] += bf2f(v[e]) * ((const float*)&cwv[e])[k];
        }
    }
    float lsum = 0.f;
    u16x8 o;
#pragma unroll
    for (int e = 0; e < 8; ++e) {
        float s = silu_f(acc[e]);
        lsum += s;
        o[e] = f2bf(s);
    }
    *(u16x8*)&xconv[(size_t)row * DINNER + d0] = o;
    const int lane = tid & 63, wave = tid >> 6;
#pragma unroll
    for (int off = 32; off; off >>= 1) lsum += __shfl_down(lsum, off);
    __shared__ float wred[4];
    if (lane == 0) wred[wave] = lsum;
    __syncthreads();
    if (tid == 0) xavg[row] = (wred[0] + wred[1] + wred[2] + wred[3]) * (1.f / DINNER);
}

// delta/B/C projections for 8 rows per block; wave w computes 12 of the 48 outputs.
__global__ __launch_bounds__(256) void dbc_kernel(
    const u16* __restrict__ xconv, const float* __restrict__ dw,
    const float* __restrict__ db, const float* __restrict__ bw,
    const float* __restrict__ cw, const float* __restrict__ A_log,
    const float* __restrict__ xavg,
    float* __restrict__ a_out, float* __restrict__ u_out, float* __restrict__ c_out) {
    const int row0 = blockIdx.x * 8;
    const int tid = threadIdx.x;
    const int lane = tid & 63;
    const int wave = tid >> 6;
    __shared__ float res[48][8];
    const float* wp[12];
#pragma unroll
    for (int i = 0; i < 12; ++i) {
        int n = wave * 12 + i;
        wp[i] = (n < 16) ? (dw + (size_t)n * DINNER)
              : (n < 32) ? (bw + (size_t)(n - 16) * DINNER)
                         : (cw + (size_t)(n - 32) * DINNER);
    }
    float acc[12][8];
#pragma unroll
    for (int i = 0; i < 12; ++i)
#pragma unroll
        for (int r = 0; r < 8; ++r) acc[i][r] = 0.f;
    for (int k = lane; k < DINNER; k += 64) {
        float xv[8];
#pragma unroll
        for (int r = 0; r < 8; ++r) xv[r] = bf2f(xconv[(size_t)(row0 + r) * DINNER + k]);
#pragma unroll
        for (int i = 0; i < 12; ++i) {
            float w = wp[i][k];
#pragma unroll
            for (int r = 0; r < 8; ++r) acc[i][r] += xv[r] * w;
        }
    }
#pragma unroll
    for (int off = 32; off; off >>= 1)
#pragma unroll
        for (int i = 0; i < 12; ++i)
#pragma unroll
            for (int r = 0; r < 8; ++r) acc[i][r] += __shfl_down(acc[i][r], off);
    if (lane == 0) {
#pragma unroll
        for (int i = 0; i < 12; ++i)
#pragma unroll
            for (int r = 0; r < 8; ++r) res[wave * 12 + i][r] = acc[i][r];
    }
    __syncthreads();
    if (tid < 128) {
        int r = tid >> 4, s = tid & 15;
        int row = row0 + r;
        float pre = res[s][r] + db[s];
        float delta = (pre > 20.f) ? pre : log1pf(__expf(pre));
        float Aa = -__expf(A_log[s]);
        a_out[row * NSTATE + s] = __expf(delta * Aa);
        u_out[row * NSTATE + s] = delta * res[16 + s][r] * xavg[row];
        c_out[row * NSTATE + s] = res[32 + s][r];
    }
}

// ---- parallel linear scan, 3 phases ----
// thread = (b, seg, s): s = tid&15, seg = (gid>>4)&63, b = gid>>10
// Phase 1: per-segment carry (P = prod a, H0 = zero-init partial result).
__global__ __launch_bounds__(256) void scan_p1(
    const float* __restrict__ a, const float* __restrict__ u,
    float* __restrict__ Pc, float* __restrict__ H0c) {
    int gid = blockIdx.x * 256 + threadIdx.x;
    int s = gid & 15, seg = (gid >> 4) & (NSEG - 1), b = gid >> 10;
    size_t base = (size_t)(b * LL + seg * SEGLEN) * NSTATE + s;
    float P = 1.f, h = 0.f;
#pragma unroll 8
    for (int t = 0; t < SEGLEN; ++t) {
        float av = a[base + (size_t)t * NSTATE];
        float uv = u[base + (size_t)t * NSTATE];
        h = fmaf(av, h, uv);
        P *= av;
    }
    int o = (b * NSEG + seg) * NSTATE + s;
    Pc[o] = P;
    H0c[o] = h;
}

// Phase 2: one wave, lane=(b,s); sequential scan over NSEG segment carries.
__global__ __launch_bounds__(64) void scan_p2(
    const float* __restrict__ Pc, const float* __restrict__ H0c,
    float* __restrict__ hstart) {
    int lane = threadIdx.x;
    int b = lane >> 4, s = lane & 15;
    float h = 0.f;
#pragma unroll 8
    for (int seg = 0; seg < NSEG; ++seg) {
        int o = (b * NSEG + seg) * NSTATE + s;
        hstart[o] = h;
        h = fmaf(Pc[o], h, H0c[o]);
    }
}

// Phase 3: re-run each segment from its true h_start; fuse y = sum_s h*c via
// 16-lane shfl_xor reduction (lanes 0..15 of each group hold s=0..15).
__global__ __launch_bounds__(256) void scan_p3(
    const float* __restrict__ a, const float* __restrict__ u,
    const float* __restrict__ c, const float* __restrict__ hstart,
    float* __restrict__ y) {
    int gid = blockIdx.x * 256 + threadIdx.x;
    int s = gid & 15, seg = (gid >> 4) & (NSEG - 1), b = gid >> 10;
    float h = hstart[(b * NSEG + seg) * NSTATE + s];
    size_t base = (size_t)(b * LL + seg * SEGLEN) * NSTATE + s;
#pragma unroll 8
    for (int t = 0; t < SEGLEN; ++t) {
        float av = a[base + (size_t)t * NSTATE];
        float uv = u[base + (size_t)t * NSTATE];
        float cv = c[base + (size_t)t * NSTATE];
        h = fmaf(av, h, uv);
        float p = h * cv;
        p += __shfl_xor(p, 1);
        p += __shfl_xor(p, 2);
        p += __shfl_xor(p, 4);
        p += __shfl_xor(p, 8);
        if (s == 0) y[b * LL + seg * SEGLEN + t] = p;
    }
}

// y_skip = y*silu(x_gate) + x_conv*D  -> bf16
__global__ __launch_bounds__(256) void gate_skip(
    const u16* __restrict__ xin, const float* __restrict__ y,
    const float* __restrict__ Dv, const u16* __restrict__ xconv,
    u16* __restrict__ yskip) {
    size_t i = ((size_t)blockIdx.x * 256 + threadIdx.x) * 8;
    int row = (int)(i >> 11);
    int d = (int)(i & (DINNER - 1));
    u16x8 g = *(const u16x8*)&xin[(size_t)row * (2 * DINNER) + DINNER + d];
    u16x8 xc = *(const u16x8*)&xconv[i];
    float yv = y[row];
    u16x8 o;
#pragma unroll
    for (int e = 0; e < 8; ++e) {
        float gv = silu_f(bf2f(g[e]));
        float v = yv * gv + bf2f(xc[e]) * Dv[d + e];
        o[e] = f2bf(v);
    }
    *(u16x8*)&yskip[i] = o;
}

extern "C" void kernel_launch(void* const* d_in, const int* in_sizes, int n_in,
                              void* d_out, int out_size, void* d_ws, size_t ws_size,
                              hipStream_t stream) {
    const float* x       = (const float*)d_in[0];
    const float* w_in    = (const float*)d_in[1];
    const float* conv_w  = (const float*)d_in[2];
    const float* conv_b  = (const float*)d_in[3];
    const float* A_log   = (const float*)d_in[4];
    const float* Dv      = (const float*)d_in[5];
    const float* delta_w = (const float*)d_in[6];
    const float* delta_b = (const float*)d_in[7];
    const float* B_w     = (const float*)d_in[8];
    const float* C_w     = (const float*)d_in[9];
    const float* out_w   = (const float*)d_in[10];
    float* out = (float*)d_out;

    u16* xb  = (u16*)d_ws;                 // 8192*1024
    u16* wb  = xb + 8388608;               // 4096*1024
    u16* owb = wb + 4194304;               // 1024*2048
    u16* xin = owb + 2097152;              // 8192*4096
    u16* xcv = xin + 33554432;             // 8192*2048
    u16* ysk = xcv + 16777216;             // 8192*2048
    float* fb     = (float*)(ysk + 16777216);
    float* abuf   = fb;                    // 8192*16
    float* ubuf   = abuf + 131072;
    float* cbuf   = ubuf + 131072;
    float* pbuf   = cbuf + 131072;         // 4*64*16
    float* h0buf  = pbuf + 4096;
    float* hsbuf  = h0buf + 4096;
    float* ybuf   = hsbuf + 4096;          // 8192
    float* avgbuf = ybuf + 8192;           // 8192

    cvt_bf16<<<4096, 256, 0, stream>>>(x, xb);
    cvt_bf16<<<2048, 256, 0, stream>>>(w_in, wb);
    cvt_bf16<<<1024, 256, 0, stream>>>(out_w, owb);

    // x_inner = x @ in_proj_w.T : (8192x1024)@(4096x1024)^T -> bf16
    gemm_bt_mfma<1><<<dim3(32, 64), 256, 0, stream>>>(xb, wb, xin, 2 * DINNER, DMODEL);

    conv_silu_avg<<<NROW, 256, 0, stream>>>(xin, conv_w, conv_b, xcv, avgbuf);
    dbc_kernel<<<NROW / 8, 256, 0, stream>>>(xcv, delta_w, delta_b, B_w, C_w,
                                             A_log, avgbuf, abuf, ubuf, cbuf);

    scan_p1<<<16, 256, 0, stream>>>(abuf, ubuf, pbuf, h0buf);
    scan_p2<<<1, 64, 0, stream>>>(pbuf, h0buf, hsbuf);
    scan_p3<<<16, 256, 0, stream>>>(abuf, ubuf, cbuf, hsbuf, ybuf);

    gate_skip<<<NROW * DINNER / 8 / 256, 256, 0, stream>>>(xin, ybuf, Dv, xcv, ysk);

    // out = y_skip @ out_proj_w.T : (8192x2048)@(1024x2048)^T -> fp32
    gemm_bt_mfma<0><<<dim3(8, 64), 256, 0, stream>>>(ysk, owb, out, DMODEL, DINNER);
}

// Round 4
// 348.912 us; speedup vs baseline: 6.0613x; 1.2402x over previous
//
#include <hip/hip_runtime.h>
#include <cmath>

#define LL 2048
#define NROW 8192
#define DMODEL 1024
#define DINNER 2048
#define NSTATE 16
#define NSEG 64
#define SEGLEN 32   // NSEG * SEGLEN == LL

typedef unsigned short u16;
typedef __attribute__((ext_vector_type(8))) unsigned short u16x8;
typedef __attribute__((ext_vector_type(8))) short short8;
typedef __attribute__((ext_vector_type(4))) float floatx4;

__device__ __forceinline__ float bf2f(u16 h) {
    unsigned u = ((unsigned)h) << 16;
    float f;
    __builtin_memcpy(&f, &u, 4);
    return f;
}
__device__ __forceinline__ u16 f2bf(float f) {
    unsigned u;
    __builtin_memcpy(&u, &f, 4);
    u = u + 0x7fffu + ((u >> 16) & 1u);
    return (u16)(u >> 16);
}
__device__ __forceinline__ float silu_f(float x) { return x / (1.f + __expf(-x)); }

// One kernel converts all six fp32->bf16 tensors (2048 elems per block).
// blocks: [0,4096) x | [4096,6144) w_in | [6144,7168) out_w |
//         [7168,7184) dw | [7184,7200) bw | [7200,7216) cw
__global__ __launch_bounds__(256) void cvt_multi(
    const float* __restrict__ s0, const float* __restrict__ s1,
    const float* __restrict__ s2, const float* __restrict__ s3,
    const float* __restrict__ s4, const float* __restrict__ s5,
    u16* __restrict__ d0, u16* __restrict__ d1, u16* __restrict__ d2,
    u16* __restrict__ d3, u16* __restrict__ d4, u16* __restrict__ d5) {
    int bid = blockIdx.x;
    const float* s;
    u16* d;
    size_t off;
    if (bid < 4096)      { s = s0; d = d0; off = (size_t)bid * 2048; }
    else if (bid < 6144) { s = s1; d = d1; off = (size_t)(bid - 4096) * 2048; }
    else if (bid < 7168) { s = s2; d = d2; off = (size_t)(bid - 6144) * 2048; }
    else if (bid < 7184) { s = s3; d = d3; off = (size_t)(bid - 7168) * 2048; }
    else if (bid < 7200) { s = s4; d = d4; off = (size_t)(bid - 7184) * 2048; }
    else                 { s = s5; d = d5; off = (size_t)(bid - 7200) * 2048; }
    size_t i = off + (size_t)threadIdx.x * 8;
    float4 a = *(const float4*)&s[i];
    float4 b = *(const float4*)&s[i + 4];
    u16x8 o;
    o[0] = f2bf(a.x); o[1] = f2bf(a.y); o[2] = f2bf(a.z); o[3] = f2bf(a.w);
    o[4] = f2bf(b.x); o[5] = f2bf(b.y); o[6] = f2bf(b.z); o[7] = f2bf(b.w);
    *(u16x8*)&d[i] = o;
}

// C[m][n] = sum_k A[m,k]*B[n,k]; A: MxK bf16, B: NxK bf16, both row-major.
// 128x128 tile, BK=32, 4 waves (2x2), each wave 64x64 via 4x4 of 16x16x32 MFMA.
// k-block XOR swizzle in LDS -> 0 bank conflicts (verified R3).
template <int OUT_BF16>
__global__ __launch_bounds__(256) void gemm_bt_mfma(
    const u16* __restrict__ A, const u16* __restrict__ B,
    void* __restrict__ Cout, int N, int K) {
    __shared__ u16 As[128 * 32];
    __shared__ u16 Bs[128 * 32];
    const int tid = threadIdx.x;
    const int lane = tid & 63;
    const int wave = tid >> 6;
    const int bm = blockIdx.y * 128;
    const int bn = blockIdx.x * 128;

    const int kbg = (lane & 3) ^ ((lane >> 3) & 3);
    const int srow = lane >> 2;
    const u16* ag[2];
    const u16* bg[2];
#pragma unroll
    for (int p = 0; p < 2; ++p) {
        int c = wave * 2 + p;
        ag[p] = A + (size_t)(bm + c * 16 + srow) * K + kbg * 8;
        bg[p] = B + (size_t)(bn + c * 16 + srow) * K + kbg * 8;
    }
    const int fr = lane & 15;
    const int kb = lane >> 4;
    const int kbs = kb ^ ((fr >> 1) & 3);
    const int wr = (wave >> 1) * 64;
    const int wc = (wave & 1) * 64;
    int aoff[4], boff[4];
#pragma unroll
    for (int i = 0; i < 4; ++i) {
        aoff[i] = (wr + i * 16 + fr) * 32 + kbs * 8;
        boff[i] = (wc + i * 16 + fr) * 32 + kbs * 8;
    }
    floatx4 acc[4][4];
#pragma unroll
    for (int i = 0; i < 4; ++i)
#pragma unroll
        for (int j = 0; j < 4; ++j) acc[i][j] = (floatx4){0.f, 0.f, 0.f, 0.f};

    for (int k0 = 0; k0 < K; k0 += 32) {
        __syncthreads();
#pragma unroll
        for (int p = 0; p < 2; ++p) {
            int c = wave * 2 + p;
            __builtin_amdgcn_global_load_lds(
                (const __attribute__((address_space(1))) void*)ag[p],
                (__attribute__((address_space(3))) void*)&As[c * 512], 16, 0, 0);
            __builtin_amdgcn_global_load_lds(
                (const __attribute__((address_space(1))) void*)bg[p],
                (__attribute__((address_space(3))) void*)&Bs[c * 512], 16, 0, 0);
            ag[p] += 32;
            bg[p] += 32;
        }
        __syncthreads();
        short8 af[4], bf[4];
#pragma unroll
        for (int i = 0; i < 4; ++i) af[i] = *(const short8*)&As[aoff[i]];
#pragma unroll
        for (int j = 0; j < 4; ++j) bf[j] = *(const short8*)&Bs[boff[j]];
#pragma unroll
        for (int i = 0; i < 4; ++i)
#pragma unroll
            for (int j = 0; j < 4; ++j)
                acc[i][j] = __builtin_amdgcn_mfma_f32_16x16x32_bf16(af[i], bf[j],
                                                                    acc[i][j], 0, 0, 0);
    }
    const int cr = (lane >> 4) * 4;
    const int cc = lane & 15;
#pragma unroll
    for (int i = 0; i < 4; ++i)
#pragma unroll
        for (int j = 0; j < 4; ++j)
#pragma unroll
            for (int r = 0; r < 4; ++r) {
                int grow = bm + wr + i * 16 + cr + r;
                int gcol = bn + wc + j * 16 + cc;
                float v = acc[i][j][r];
                if (OUT_BF16)
                    ((u16*)Cout)[(size_t)grow * N + gcol] = f2bf(v);
                else
                    ((float*)Cout)[(size_t)grow * N + gcol] = v;
            }
}

// depthwise causal conv (DC=4) + bias + silu + row-mean.
// Block = (b, 16-row l-chunk); sliding 4-row window in registers ->
// read amplification 19/16 instead of 4x.
__global__ __launch_bounds__(256) void conv_silu_avg(
    const u16* __restrict__ xin, const float* __restrict__ cw,
    const float* __restrict__ cb, u16* __restrict__ xconv,
    float* __restrict__ xavg) {
    const int blk = blockIdx.x;        // 512 blocks
    const int b = blk >> 7;
    const int lc = blk & 127;
    const int row0 = b * LL + lc * 16;
    const int tid = threadIdx.x;
    const int lane = tid & 63, wave = tid >> 6;
    const int d0 = tid * 8;
    float4 cwv[8];
    float cbv[8];
#pragma unroll
    for (int e = 0; e < 8; ++e) cwv[e] = *(const float4*)&cw[(d0 + e) * 4];
#pragma unroll
    for (int e = 0; e < 8; e += 4) {
        float4 c = *(const float4*)&cb[d0 + e];
        cbv[e] = c.x; cbv[e + 1] = c.y; cbv[e + 2] = c.z; cbv[e + 3] = c.w;
    }
    u16x8 w0, w1, w2;
    if (lc == 0) {
        w0 = (u16x8)0; w1 = (u16x8)0; w2 = (u16x8)0;
    } else {
        w0 = *(const u16x8*)&xin[(size_t)(row0 - 3) * (2 * DINNER) + d0];
        w1 = *(const u16x8*)&xin[(size_t)(row0 - 2) * (2 * DINNER) + d0];
        w2 = *(const u16x8*)&xin[(size_t)(row0 - 1) * (2 * DINNER) + d0];
    }
    float sums[16];
#pragma unroll
    for (int t = 0; t < 16; ++t) {
        u16x8 cur = *(const u16x8*)&xin[(size_t)(row0 + t) * (2 * DINNER) + d0];
        float lsum = 0.f;
        u16x8 o;
#pragma unroll
        for (int e = 0; e < 8; ++e) {
            float acc = cbv[e];
            acc += bf2f(w0[e]) * cwv[e].x;
            acc += bf2f(w1[e]) * cwv[e].y;
            acc += bf2f(w2[e]) * cwv[e].z;
            acc += bf2f(cur[e]) * cwv[e].w;
            float s = silu_f(acc);
            lsum += s;
            o[e] = f2bf(s);
        }
        *(u16x8*)&xconv[(size_t)(row0 + t) * DINNER + d0] = o;
        sums[t] = lsum;
        w0 = w1; w1 = w2; w2 = cur;
    }
#pragma unroll
    for (int off = 32; off; off >>= 1)
#pragma unroll
        for (int t = 0; t < 16; ++t) sums[t] += __shfl_down(sums[t], off);
    __shared__ float wred[4][16];
    if (lane == 0) {
#pragma unroll
        for (int t = 0; t < 16; ++t) wred[wave][t] = sums[t];
    }
    __syncthreads();
    if (tid < 16)
        xavg[row0 + tid] = (wred[0][tid] + wred[1][tid] + wred[2][tid] + wred[3][tid]) *
                           (1.f / DINNER);
}

// delta/B/C projections via MFMA: thin GEMM (8192 x 48 x 2048), B = wcat (48x2048
// bf16 = [delta_w; B_w; C_w]). 64 blocks x 128 rows. Wave handles 32 rows x 48 cols
// (2 m-tiles x 3 n-tiles). n-tile 0/1/2 give delta/Bs/Cs at the SAME (lane,reg) ->
// epilogue is lane-local.
__global__ __launch_bounds__(256) void dbc_mfma(
    const u16* __restrict__ xconv, const u16* __restrict__ wcat,
    const float* __restrict__ db, const float* __restrict__ A_log,
    const float* __restrict__ xavg,
    float* __restrict__ a_out, float* __restrict__ u_out, float* __restrict__ c_out) {
    __shared__ u16 As[128 * 32];
    __shared__ u16 Bs[48 * 32];
    const int tid = threadIdx.x;
    const int lane = tid & 63;
    const int wave = tid >> 6;
    const int bm = blockIdx.x * 128;

    const int kbg = (lane & 3) ^ ((lane >> 3) & 3);
    const int srow = lane >> 2;
    const u16* ag[2];
#pragma unroll
    for (int p = 0; p < 2; ++p) {
        int c = wave * 2 + p;
        ag[p] = xconv + (size_t)(bm + c * 16 + srow) * DINNER + kbg * 8;
    }
    const u16* bgp = wcat + (size_t)(wave * 16 + srow) * DINNER + kbg * 8;  // wave<3 only
    const int fr = lane & 15;
    const int kb = lane >> 4;
    const int kbs = kb ^ ((fr >> 1) & 3);
    int aoff[2], boff[3];
#pragma unroll
    for (int mi = 0; mi < 2; ++mi) aoff[mi] = (wave * 32 + mi * 16 + fr) * 32 + kbs * 8;
#pragma unroll
    for (int ni = 0; ni < 3; ++ni) boff[ni] = (ni * 16 + fr) * 32 + kbs * 8;

    floatx4 acc[2][3];
#pragma unroll
    for (int mi = 0; mi < 2; ++mi)
#pragma unroll
        for (int ni = 0; ni < 3; ++ni) acc[mi][ni] = (floatx4){0.f, 0.f, 0.f, 0.f};

    for (int k0 = 0; k0 < DINNER; k0 += 32) {
        __syncthreads();
#pragma unroll
        for (int p = 0; p < 2; ++p) {
            int c = wave * 2 + p;
            __builtin_amdgcn_global_load_lds(
                (const __attribute__((address_space(1))) void*)ag[p],
                (__attribute__((address_space(3))) void*)&As[c * 512], 16, 0, 0);
            ag[p] += 32;
        }
        if (wave < 3) {
            __builtin_amdgcn_global_load_lds(
                (const __attribute__((address_space(1))) void*)bgp,
                (__attribute__((address_space(3))) void*)&Bs[wave * 512], 16, 0, 0);
            bgp += 32;
        }
        __syncthreads();
        short8 af[2], bf[3];
#pragma unroll
        for (int mi = 0; mi < 2; ++mi) af[mi] = *(const short8*)&As[aoff[mi]];
#pragma unroll
        for (int ni = 0; ni < 3; ++ni) bf[ni] = *(const short8*)&Bs[boff[ni]];
#pragma unroll
        for (int mi = 0; mi < 2; ++mi)
#pragma unroll
            for (int ni = 0; ni < 3; ++ni)
                acc[mi][ni] = __builtin_amdgcn_mfma_f32_16x16x32_bf16(af[mi], bf[ni],
                                                                      acc[mi][ni], 0, 0, 0);
    }
    const int cr = (lane >> 4) * 4;
    const int s = lane & 15;
    const float Aa = -__expf(A_log[s]);
    const float dbs = db[s];
#pragma unroll
    for (int mi = 0; mi < 2; ++mi)
#pragma unroll
        for (int r = 0; r < 4; ++r) {
            int row = bm + wave * 32 + mi * 16 + cr + r;
            float pre = acc[mi][0][r] + dbs;
            float delta = (pre > 20.f) ? pre : log1pf(__expf(pre));
            a_out[row * NSTATE + s] = __expf(delta * Aa);
            u_out[row * NSTATE + s] = delta * acc[mi][1][r] * xavg[row];
            c_out[row * NSTATE + s] = acc[mi][2][r];
        }
}

// ---- parallel linear scan, 3 phases ----
__global__ __launch_bounds__(256) void scan_p1(
    const float* __restrict__ a, const float* __restrict__ u,
    float* __restrict__ Pc, float* __restrict__ H0c) {
    int gid = blockIdx.x * 256 + threadIdx.x;
    int s = gid & 15, seg = (gid >> 4) & (NSEG - 1), b = gid >> 10;
    size_t base = (size_t)(b * LL + seg * SEGLEN) * NSTATE + s;
    float P = 1.f, h = 0.f;
#pragma unroll 8
    for (int t = 0; t < SEGLEN; ++t) {
        float av = a[base + (size_t)t * NSTATE];
        float uv = u[base + (size_t)t * NSTATE];
        h = fmaf(av, h, uv);
        P *= av;
    }
    int o = (b * NSEG + seg) * NSTATE + s;
    Pc[o] = P;
    H0c[o] = h;
}

__global__ __launch_bounds__(64) void scan_p2(
    const float* __restrict__ Pc, const float* __restrict__ H0c,
    float* __restrict__ hstart) {
    int lane = threadIdx.x;
    int b = lane >> 4, s = lane & 15;
    float h = 0.f;
#pragma unroll 8
    for (int seg = 0; seg < NSEG; ++seg) {
        int o = (b * NSEG + seg) * NSTATE + s;
        hstart[o] = h;
        h = fmaf(Pc[o], h, H0c[o]);
    }
}

__global__ __launch_bounds__(256) void scan_p3(
    const float* __restrict__ a, const float* __restrict__ u,
    const float* __restrict__ c, const float* __restrict__ hstart,
    float* __restrict__ y) {
    int gid = blockIdx.x * 256 + threadIdx.x;
    int s = gid & 15, seg = (gid >> 4) & (NSEG - 1), b = gid >> 10;
    float h = hstart[(b * NSEG + seg) * NSTATE + s];
    size_t base = (size_t)(b * LL + seg * SEGLEN) * NSTATE + s;
#pragma unroll 8
    for (int t = 0; t < SEGLEN; ++t) {
        float av = a[base + (size_t)t * NSTATE];
        float uv = u[base + (size_t)t * NSTATE];
        float cv = c[base + (size_t)t * NSTATE];
        h = fmaf(av, h, uv);
        float p = h * cv;
        p += __shfl_xor(p, 1);
        p += __shfl_xor(p, 2);
        p += __shfl_xor(p, 4);
        p += __shfl_xor(p, 8);
        if (s == 0) y[b * LL + seg * SEGLEN + t] = p;
    }
}

// y_skip = y*silu(x_gate) + x_conv*D  -> bf16
__global__ __launch_bounds__(256) void gate_skip(
    const u16* __restrict__ xin, const float* __restrict__ y,
    const float* __restrict__ Dv, const u16* __restrict__ xconv,
    u16* __restrict__ yskip) {
    size_t i = ((size_t)blockIdx.x * 256 + threadIdx.x) * 8;
    int row = (int)(i >> 11);
    int d = (int)(i & (DINNER - 1));
    u16x8 g = *(const u16x8*)&xin[(size_t)row * (2 * DINNER) + DINNER + d];
    u16x8 xc = *(const u16x8*)&xconv[i];
    float yv = y[row];
    u16x8 o;
#pragma unroll
    for (int e = 0; e < 8; ++e) {
        float gv = silu_f(bf2f(g[e]));
        float v = yv * gv + bf2f(xc[e]) * Dv[d + e];
        o[e] = f2bf(v);
    }
    *(u16x8*)&yskip[i] = o;
}

extern "C" void kernel_launch(void* const* d_in, const int* in_sizes, int n_in,
                              void* d_out, int out_size, void* d_ws, size_t ws_size,
                              hipStream_t stream) {
    const float* x       = (const float*)d_in[0];
    const float* w_in    = (const float*)d_in[1];
    const float* conv_w  = (const float*)d_in[2];
    const float* conv_b  = (const float*)d_in[3];
    const float* A_log   = (const float*)d_in[4];
    const float* Dv      = (const float*)d_in[5];
    const float* delta_w = (const float*)d_in[6];
    const float* delta_b = (const float*)d_in[7];
    const float* B_w     = (const float*)d_in[8];
    const float* C_w     = (const float*)d_in[9];
    const float* out_w   = (const float*)d_in[10];
    float* out = (float*)d_out;

    u16* xb  = (u16*)d_ws;                 // 8192*1024
    u16* wb  = xb + 8388608;               // 4096*1024
    u16* owb = wb + 4194304;               // 1024*2048
    u16* wsb = owb + 2097152;              // 48*2048 (concat dw,bw,cw)
    u16* xin = wsb + 98304;                // 8192*4096
    u16* xcv = xin + 33554432;             // 8192*2048
    u16* ysk = xcv + 16777216;             // 8192*2048
    float* fb     = (float*)(ysk + 16777216);
    float* abuf   = fb;                    // 8192*16
    float* ubuf   = abuf + 131072;
    float* cbuf   = ubuf + 131072;
    float* pbuf   = cbuf + 131072;         // 4*64*16
    float* h0buf  = pbuf + 4096;
    float* hsbuf  = h0buf + 4096;
    float* ybuf   = hsbuf + 4096;          // 8192
    float* avgbuf = ybuf + 8192;           // 8192

    cvt_multi<<<7216, 256, 0, stream>>>(x, w_in, out_w, delta_w, B_w, C_w,
                                        xb, wb, owb, wsb, wsb + 32768, wsb + 65536);

    // x_inner = x @ in_proj_w.T : (8192x1024)@(4096x1024)^T -> bf16
    gemm_bt_mfma<1><<<dim3(32, 64), 256, 0, stream>>>(xb, wb, xin, 2 * DINNER, DMODEL);

    conv_silu_avg<<<512, 256, 0, stream>>>(xin, conv_w, conv_b, xcv, avgbuf);
    dbc_mfma<<<64, 256, 0, stream>>>(xcv, wsb, delta_b, A_log, avgbuf,
                                     abuf, ubuf, cbuf);

    scan_p1<<<16, 256, 0, stream>>>(abuf, ubuf, pbuf, h0buf);
    scan_p2<<<1, 64, 0, stream>>>(pbuf, h0buf, hsbuf);
    scan_p3<<<16, 256, 0, stream>>>(abuf, ubuf, cbuf, hsbuf, ybuf);

    gate_skip<<<NROW * DINNER / 8 / 256, 256, 0, stream>>>(xin, ybuf, Dv, xcv, ysk);

    // out = y_skip @ out_proj_w.T : (8192x2048)@(1024x2048)^T -> fp32
    gemm_bt_mfma<0><<<dim3(8, 64), 256, 0, stream>>>(ysk, owb, out, DMODEL, DINNER);
}

// Round 5
// 337.442 us; speedup vs baseline: 6.2673x; 1.0340x over previous
//
#include <hip/hip_runtime.h>
#include <cmath>

#define LL 2048
#define NROW 8192
#define DMODEL 1024
#define DINNER 2048
#define NSTATE 16
#define NSEG 64
#define SEGLEN 32   // NSEG * SEGLEN == LL

typedef unsigned short u16;
typedef __attribute__((ext_vector_type(8))) unsigned short u16x8;
typedef __attribute__((ext_vector_type(8))) short short8;
typedef __attribute__((ext_vector_type(4))) float floatx4;
typedef __attribute__((ext_vector_type(16))) float floatx16;

__device__ __forceinline__ float bf2f(u16 h) {
    unsigned u = ((unsigned)h) << 16;
    float f;
    __builtin_memcpy(&f, &u, 4);
    return f;
}
__device__ __forceinline__ u16 f2bf(float f) {
    unsigned u;
    __builtin_memcpy(&u, &f, 4);
    u = u + 0x7fffu + ((u >> 16) & 1u);
    return (u16)(u >> 16);
}
__device__ __forceinline__ float silu_f(float x) { return x / (1.f + __expf(-x)); }

// One kernel converts all six fp32->bf16 tensors (2048 elems per block).
__global__ __launch_bounds__(256) void cvt_multi(
    const float* __restrict__ s0, const float* __restrict__ s1,
    const float* __restrict__ s2, const float* __restrict__ s3,
    const float* __restrict__ s4, const float* __restrict__ s5,
    u16* __restrict__ d0, u16* __restrict__ d1, u16* __restrict__ d2,
    u16* __restrict__ d3, u16* __restrict__ d4, u16* __restrict__ d5) {
    int bid = blockIdx.x;
    const float* s;
    u16* d;
    size_t off;
    if (bid < 4096)      { s = s0; d = d0; off = (size_t)bid * 2048; }
    else if (bid < 6144) { s = s1; d = d1; off = (size_t)(bid - 4096) * 2048; }
    else if (bid < 7168) { s = s2; d = d2; off = (size_t)(bid - 6144) * 2048; }
    else if (bid < 7184) { s = s3; d = d3; off = (size_t)(bid - 7168) * 2048; }
    else if (bid < 7200) { s = s4; d = d4; off = (size_t)(bid - 7184) * 2048; }
    else                 { s = s5; d = d5; off = (size_t)(bid - 7200) * 2048; }
    size_t i = off + (size_t)threadIdx.x * 8;
    float4 a = *(const float4*)&s[i];
    float4 b = *(const float4*)&s[i + 4];
    u16x8 o;
    o[0] = f2bf(a.x); o[1] = f2bf(a.y); o[2] = f2bf(a.z); o[3] = f2bf(a.w);
    o[4] = f2bf(b.x); o[5] = f2bf(b.y); o[6] = f2bf(b.z); o[7] = f2bf(b.w);
    *(u16x8*)&d[i] = o;
}

// C[m][n] = sum_k A[m,k]*B[n,k]; A: MxK bf16, B: NxK bf16, row-major.
// 128x128 tile, BK=32, 4 waves (2x2), each wave 64x64 via 2x2 of 32x32x16 MFMA
// (2 K-steps per BK). LDS k-block XOR swizzle -> 0 bank conflicts (verified R3;
// swizzle depends only on row mod 8, so 32-row frags keep the same pattern).
template <int OUT_BF16>
__global__ __launch_bounds__(256) void gemm_bt_mfma(
    const u16* __restrict__ A, const u16* __restrict__ B,
    void* __restrict__ Cout, int N, int K) {
    __shared__ u16 As[128 * 32];
    __shared__ u16 Bs[128 * 32];
    const int tid = threadIdx.x;
    const int lane = tid & 63;
    const int wave = tid >> 6;
    const int bm = blockIdx.y * 128;
    const int bn = blockIdx.x * 128;

    // staging: chunk c=wave*2+p covers tile rows [c*16, c*16+16)
    const int kbg = (lane & 3) ^ ((lane >> 3) & 3);
    const int srow = lane >> 2;
    const u16* ag[2];
    const u16* bg[2];
#pragma unroll
    for (int p = 0; p < 2; ++p) {
        int c = wave * 2 + p;
        ag[p] = A + (size_t)(bm + c * 16 + srow) * K + kbg * 8;
        bg[p] = B + (size_t)(bn + c * 16 + srow) * K + kbg * 8;
    }
    // fragment offsets: A frag (mi,kh): row = wr + mi*32 + (lane&31),
    // global k-block = kh*2 + (lane>>5), stored pos = kb ^ ((row>>1)&3)
    const int frow = lane & 31;
    const int khi = lane >> 5;
    const int wr = (wave >> 1) * 64;
    const int wc = (wave & 1) * 64;
    int aoff[2][2], boff[2][2];
#pragma unroll
    for (int mi = 0; mi < 2; ++mi)
#pragma unroll
        for (int kh = 0; kh < 2; ++kh) {
            int rA = wr + mi * 32 + frow;
            int rB = wc + mi * 32 + frow;
            int kb = kh * 2 + khi;
            aoff[mi][kh] = rA * 32 + (kb ^ ((rA >> 1) & 3)) * 8;
            boff[mi][kh] = rB * 32 + (kb ^ ((rB >> 1) & 3)) * 8;
        }
    floatx16 acc[2][2];
#pragma unroll
    for (int i = 0; i < 2; ++i)
#pragma unroll
        for (int j = 0; j < 2; ++j) acc[i][j] = (floatx16)(0.f);

    for (int k0 = 0; k0 < K; k0 += 32) {
        __syncthreads();
#pragma unroll
        for (int p = 0; p < 2; ++p) {
            int c = wave * 2 + p;
            __builtin_amdgcn_global_load_lds(
                (const __attribute__((address_space(1))) void*)ag[p],
                (__attribute__((address_space(3))) void*)&As[c * 512], 16, 0, 0);
            __builtin_amdgcn_global_load_lds(
                (const __attribute__((address_space(1))) void*)bg[p],
                (__attribute__((address_space(3))) void*)&Bs[c * 512], 16, 0, 0);
            ag[p] += 32;
            bg[p] += 32;
        }
        __syncthreads();
        short8 af[2][2], bf[2][2];
#pragma unroll
        for (int mi = 0; mi < 2; ++mi)
#pragma unroll
            for (int kh = 0; kh < 2; ++kh) {
                af[mi][kh] = *(const short8*)&As[aoff[mi][kh]];
                bf[mi][kh] = *(const short8*)&Bs[boff[mi][kh]];
            }
#pragma unroll
        for (int kh = 0; kh < 2; ++kh)
#pragma unroll
            for (int mi = 0; mi < 2; ++mi)
#pragma unroll
                for (int ni = 0; ni < 2; ++ni)
                    acc[mi][ni] = __builtin_amdgcn_mfma_f32_32x32x16_bf16(
                        af[mi][kh], bf[ni][kh], acc[mi][ni], 0, 0, 0);
    }
    // C/D layout (m74/m101): col = lane&31, row = (reg&3) + 8*(reg>>2) + 4*(lane>>5)
    const int cc = lane & 31;
    const int rbase = 4 * (lane >> 5);
#pragma unroll
    for (int mi = 0; mi < 2; ++mi)
#pragma unroll
        for (int ni = 0; ni < 2; ++ni)
#pragma unroll
            for (int r = 0; r < 16; ++r) {
                int grow = bm + wr + mi * 32 + (r & 3) + 8 * (r >> 2) + rbase;
                int gcol = bn + wc + ni * 32 + cc;
                float v = acc[mi][ni][r];
                if (OUT_BF16)
                    ((u16*)Cout)[(size_t)grow * N + gcol] = f2bf(v);
                else
                    ((float*)Cout)[(size_t)grow * N + gcol] = v;
            }
}

// depthwise causal conv (DC=4) + bias + silu + row-mean.
__global__ __launch_bounds__(256) void conv_silu_avg(
    const u16* __restrict__ xin, const float* __restrict__ cw,
    const float* __restrict__ cb, u16* __restrict__ xconv,
    float* __restrict__ xavg) {
    const int blk = blockIdx.x;        // 512 blocks
    const int b = blk >> 7;
    const int lc = blk & 127;
    const int row0 = b * LL + lc * 16;
    const int tid = threadIdx.x;
    const int lane = tid & 63, wave = tid >> 6;
    const int d0 = tid * 8;
    float4 cwv[8];
    float cbv[8];
#pragma unroll
    for (int e = 0; e < 8; ++e) cwv[e] = *(const float4*)&cw[(d0 + e) * 4];
#pragma unroll
    for (int e = 0; e < 8; e += 4) {
        float4 c = *(const float4*)&cb[d0 + e];
        cbv[e] = c.x; cbv[e + 1] = c.y; cbv[e + 2] = c.z; cbv[e + 3] = c.w;
    }
    u16x8 w0, w1, w2;
    if (lc == 0) {
        w0 = (u16x8)0; w1 = (u16x8)0; w2 = (u16x8)0;
    } else {
        w0 = *(const u16x8*)&xin[(size_t)(row0 - 3) * (2 * DINNER) + d0];
        w1 = *(const u16x8*)&xin[(size_t)(row0 - 2) * (2 * DINNER) + d0];
        w2 = *(const u16x8*)&xin[(size_t)(row0 - 1) * (2 * DINNER) + d0];
    }
    float sums[16];
#pragma unroll
    for (int t = 0; t < 16; ++t) {
        u16x8 cur = *(const u16x8*)&xin[(size_t)(row0 + t) * (2 * DINNER) + d0];
        float lsum = 0.f;
        u16x8 o;
#pragma unroll
        for (int e = 0; e < 8; ++e) {
            float acc = cbv[e];
            acc += bf2f(w0[e]) * cwv[e].x;
            acc += bf2f(w1[e]) * cwv[e].y;
            acc += bf2f(w2[e]) * cwv[e].z;
            acc += bf2f(cur[e]) * cwv[e].w;
            float s = silu_f(acc);
            lsum += s;
            o[e] = f2bf(s);
        }
        *(u16x8*)&xconv[(size_t)(row0 + t) * DINNER + d0] = o;
        sums[t] = lsum;
        w0 = w1; w1 = w2; w2 = cur;
    }
#pragma unroll
    for (int off = 32; off; off >>= 1)
#pragma unroll
        for (int t = 0; t < 16; ++t) sums[t] += __shfl_down(sums[t], off);
    __shared__ float wred[4][16];
    if (lane == 0) {
#pragma unroll
        for (int t = 0; t < 16; ++t) wred[wave][t] = sums[t];
    }
    __syncthreads();
    if (tid < 16)
        xavg[row0 + tid] = (wred[0][tid] + wred[1][tid] + wred[2][tid] + wred[3][tid]) *
                           (1.f / DINNER);
}

// delta/B/C projections via MFMA (16x16x32): thin GEMM (8192 x 48 x 2048).
__global__ __launch_bounds__(256) void dbc_mfma(
    const u16* __restrict__ xconv, const u16* __restrict__ wcat,
    const float* __restrict__ db, const float* __restrict__ A_log,
    const float* __restrict__ xavg,
    float* __restrict__ a_out, float* __restrict__ u_out, float* __restrict__ c_out) {
    __shared__ u16 As[128 * 32];
    __shared__ u16 Bs[48 * 32];
    const int tid = threadIdx.x;
    const int lane = tid & 63;
    const int wave = tid >> 6;
    const int bm = blockIdx.x * 128;

    const int kbg = (lane & 3) ^ ((lane >> 3) & 3);
    const int srow = lane >> 2;
    const u16* ag[2];
#pragma unroll
    for (int p = 0; p < 2; ++p) {
        int c = wave * 2 + p;
        ag[p] = xconv + (size_t)(bm + c * 16 + srow) * DINNER + kbg * 8;
    }
    const u16* bgp = wcat + (size_t)(wave * 16 + srow) * DINNER + kbg * 8;  // wave<3 only
    const int fr = lane & 15;
    const int kb = lane >> 4;
    const int kbs = kb ^ ((fr >> 1) & 3);
    int aoff[2], boff[3];
#pragma unroll
    for (int mi = 0; mi < 2; ++mi) aoff[mi] = (wave * 32 + mi * 16 + fr) * 32 + kbs * 8;
#pragma unroll
    for (int ni = 0; ni < 3; ++ni) boff[ni] = (ni * 16 + fr) * 32 + kbs * 8;

    floatx4 acc[2][3];
#pragma unroll
    for (int mi = 0; mi < 2; ++mi)
#pragma unroll
        for (int ni = 0; ni < 3; ++ni) acc[mi][ni] = (floatx4){0.f, 0.f, 0.f, 0.f};

    for (int k0 = 0; k0 < DINNER; k0 += 32) {
        __syncthreads();
#pragma unroll
        for (int p = 0; p < 2; ++p) {
            int c = wave * 2 + p;
            __builtin_amdgcn_global_load_lds(
                (const __attribute__((address_space(1))) void*)ag[p],
                (__attribute__((address_space(3))) void*)&As[c * 512], 16, 0, 0);
            ag[p] += 32;
        }
        if (wave < 3) {
            __builtin_amdgcn_global_load_lds(
                (const __attribute__((address_space(1))) void*)bgp,
                (__attribute__((address_space(3))) void*)&Bs[wave * 512], 16, 0, 0);
            bgp += 32;
        }
        __syncthreads();
        short8 af[2], bf[3];
#pragma unroll
        for (int mi = 0; mi < 2; ++mi) af[mi] = *(const short8*)&As[aoff[mi]];
#pragma unroll
        for (int ni = 0; ni < 3; ++ni) bf[ni] = *(const short8*)&Bs[boff[ni]];
#pragma unroll
        for (int mi = 0; mi < 2; ++mi)
#pragma unroll
            for (int ni = 0; ni < 3; ++ni)
                acc[mi][ni] = __builtin_amdgcn_mfma_f32_16x16x32_bf16(af[mi], bf[ni],
                                                                      acc[mi][ni], 0, 0, 0);
    }
    const int cr = (lane >> 4) * 4;
    const int s = lane & 15;
    const float Aa = -__expf(A_log[s]);
    const float dbs = db[s];
#pragma unroll
    for (int mi = 0; mi < 2; ++mi)
#pragma unroll
        for (int r = 0; r < 4; ++r) {
            int row = bm + wave * 32 + mi * 16 + cr + r;
            float pre = acc[mi][0][r] + dbs;
            float delta = (pre > 20.f) ? pre : log1pf(__expf(pre));
            a_out[row * NSTATE + s] = __expf(delta * Aa);
            u_out[row * NSTATE + s] = delta * acc[mi][1][r] * xavg[row];
            c_out[row * NSTATE + s] = acc[mi][2][r];
        }
}

// ---- parallel linear scan, 3 phases ----
__global__ __launch_bounds__(256) void scan_p1(
    const float* __restrict__ a, const float* __restrict__ u,
    float* __restrict__ Pc, float* __restrict__ H0c) {
    int gid = blockIdx.x * 256 + threadIdx.x;
    int s = gid & 15, seg = (gid >> 4) & (NSEG - 1), b = gid >> 10;
    size_t base = (size_t)(b * LL + seg * SEGLEN) * NSTATE + s;
    float P = 1.f, h = 0.f;
#pragma unroll 8
    for (int t = 0; t < SEGLEN; ++t) {
        float av = a[base + (size_t)t * NSTATE];
        float uv = u[base + (size_t)t * NSTATE];
        h = fmaf(av, h, uv);
        P *= av;
    }
    int o = (b * NSEG + seg) * NSTATE + s;
    Pc[o] = P;
    H0c[o] = h;
}

__global__ __launch_bounds__(64) void scan_p2(
    const float* __restrict__ Pc, const float* __restrict__ H0c,
    float* __restrict__ hstart) {
    int lane = threadIdx.x;
    int b = lane >> 4, s = lane & 15;
    float h = 0.f;
#pragma unroll 8
    for (int seg = 0; seg < NSEG; ++seg) {
        int o = (b * NSEG + seg) * NSTATE + s;
        hstart[o] = h;
        h = fmaf(Pc[o], h, H0c[o]);
    }
}

__global__ __launch_bounds__(256) void scan_p3(
    const float* __restrict__ a, const float* __restrict__ u,
    const float* __restrict__ c, const float* __restrict__ hstart,
    float* __restrict__ y) {
    int gid = blockIdx.x * 256 + threadIdx.x;
    int s = gid & 15, seg = (gid >> 4) & (NSEG - 1), b = gid >> 10;
    float h = hstart[(b * NSEG + seg) * NSTATE + s];
    size_t base = (size_t)(b * LL + seg * SEGLEN) * NSTATE + s;
#pragma unroll 8
    for (int t = 0; t < SEGLEN; ++t) {
        float av = a[base + (size_t)t * NSTATE];
        float uv = u[base + (size_t)t * NSTATE];
        float cv = c[base + (size_t)t * NSTATE];
        h = fmaf(av, h, uv);
        float p = h * cv;
        p += __shfl_xor(p, 1);
        p += __shfl_xor(p, 2);
        p += __shfl_xor(p, 4);
        p += __shfl_xor(p, 8);
        if (s == 0) y[b * LL + seg * SEGLEN + t] = p;
    }
}

// y_skip = y*silu(x_gate) + x_conv*D  -> bf16
__global__ __launch_bounds__(256) void gate_skip(
    const u16* __restrict__ xin, const float* __restrict__ y,
    const float* __restrict__ Dv, const u16* __restrict__ xconv,
    u16* __restrict__ yskip) {
    size_t i = ((size_t)blockIdx.x * 256 + threadIdx.x) * 8;
    int row = (int)(i >> 11);
    int d = (int)(i & (DINNER - 1));
    u16x8 g = *(const u16x8*)&xin[(size_t)row * (2 * DINNER) + DINNER + d];
    u16x8 xc = *(const u16x8*)&xconv[i];
    float yv = y[row];
    u16x8 o;
#pragma unroll
    for (int e = 0; e < 8; ++e) {
        float gv = silu_f(bf2f(g[e]));
        float v = yv * gv + bf2f(xc[e]) * Dv[d + e];
        o[e] = f2bf(v);
    }
    *(u16x8*)&yskip[i] = o;
}

extern "C" void kernel_launch(void* const* d_in, const int* in_sizes, int n_in,
                              void* d_out, int out_size, void* d_ws, size_t ws_size,
                              hipStream_t stream) {
    const float* x       = (const float*)d_in[0];
    const float* w_in    = (const float*)d_in[1];
    const float* conv_w  = (const float*)d_in[2];
    const float* conv_b  = (const float*)d_in[3];
    const float* A_log   = (const float*)d_in[4];
    const float* Dv      = (const float*)d_in[5];
    const float* delta_w = (const float*)d_in[6];
    const float* delta_b = (const float*)d_in[7];
    const float* B_w     = (const float*)d_in[8];
    const float* C_w     = (const float*)d_in[9];
    const float* out_w   = (const float*)d_in[10];
    float* out = (float*)d_out;

    u16* xb  = (u16*)d_ws;                 // 8192*1024
    u16* wb  = xb + 8388608;               // 4096*1024
    u16* owb = wb + 4194304;               // 1024*2048
    u16* wsb = owb + 2097152;              // 48*2048 (concat dw,bw,cw)
    u16* xin = wsb + 98304;                // 8192*4096
    u16* xcv = xin + 33554432;             // 8192*2048
    u16* ysk = xcv + 16777216;             // 8192*2048
    float* fb     = (float*)(ysk + 16777216);
    float* abuf   = fb;                    // 8192*16
    float* ubuf   = abuf + 131072;
    float* cbuf   = ubuf + 131072;
    float* pbuf   = cbuf + 131072;         // 4*64*16
    float* h0buf  = pbuf + 4096;
    float* hsbuf  = h0buf + 4096;
    float* ybuf   = hsbuf + 4096;          // 8192
    float* avgbuf = ybuf + 8192;           // 8192

    cvt_multi<<<7216, 256, 0, stream>>>(x, w_in, out_w, delta_w, B_w, C_w,
                                        xb, wb, owb, wsb, wsb + 32768, wsb + 65536);

    // x_inner = x @ in_proj_w.T : (8192x1024)@(4096x1024)^T -> bf16
    gemm_bt_mfma<1><<<dim3(32, 64), 256, 0, stream>>>(xb, wb, xin, 2 * DINNER, DMODEL);

    conv_silu_avg<<<512, 256, 0, stream>>>(xin, conv_w, conv_b, xcv, avgbuf);
    dbc_mfma<<<64, 256, 0, stream>>>(xcv, wsb, delta_b, A_log, avgbuf,
                                     abuf, ubuf, cbuf);

    scan_p1<<<16, 256, 0, stream>>>(abuf, ubuf, pbuf, h0buf);
    scan_p2<<<1, 64, 0, stream>>>(pbuf, h0buf, hsbuf);
    scan_p3<<<16, 256, 0, stream>>>(abuf, ubuf, cbuf, hsbuf, ybuf);

    gate_skip<<<NROW * DINNER / 8 / 256, 256, 0, stream>>>(xin, ybuf, Dv, xcv, ysk);

    // out = y_skip @ out_proj_w.T : (8192x2048)@(1024x2048)^T -> fp32
    gemm_bt_mfma<0><<<dim3(8, 64), 256, 0, stream>>>(ysk, owb, out, DMODEL, DINNER);
}